// Round 1
// baseline (166.282 us; speedup 1.0000x reference)
//
#include <hip/hip_runtime.h>

#define L 4096
#define LMASK 4095
#define NCELL (L * L)
#define TILE 32
#define HALO 2
#define SDIM (TILE + 2 * HALO)   // 36

__global__ __launch_bounds__(256) void spgg_qlearn_kernel(
    const int*    __restrict__ type_t,     // (L,L) int32, 0/1
    const float4* __restrict__ qtab,       // (N,2,2) f32 -> float4 per cell
    const float2* __restrict__ rnd,        // (N,2) f32
    const int*    __restrict__ rtype,      // (L,L) int32 0/1
    const float*  __restrict__ eps,        // (L,L) f32
    float*        __restrict__ out_type,   // (L,L) f32
    float4*       __restrict__ out_q,      // (N,2,2) f32
    float*        __restrict__ out_profit) // (L,L) f32
{
    __shared__ int s_t[SDIM * SDIM];

    const int tx = threadIdx.x;            // 0..31
    const int ty = threadIdx.y;            // 0..7
    const int tid = ty * 32 + tx;
    const int tileR0 = blockIdx.y * TILE;
    const int tileC0 = blockIdx.x * TILE;

    // Stage type tile with halo 2 (torus wrap via & mask, L = 2^12)
    for (int idx = tid; idx < SDIM * SDIM; idx += 256) {
        int ly = idx / SDIM;
        int lx = idx - ly * SDIM;
        int gr = (tileR0 + ly - HALO) & LMASK;
        int gc = (tileC0 + lx - HALO) & LMASK;
        s_t[idx] = type_t[gr * L + gc];
    }
    __syncthreads();

    #pragma unroll
    for (int k = 0; k < 4; ++k) {
        const int r = ty + k * 8;          // 0..31
        const int c = tx;
        const int sr = r + HALO;
        const int sc = c + HALO;

        // 13-point stencil == neigh5(neigh5(c)) weights {5,2,2,1}
        const int t00 = s_t[sr * SDIM + sc];
        const int cross = s_t[(sr - 1) * SDIM + sc] + s_t[(sr + 1) * SDIM + sc]
                        + s_t[sr * SDIM + sc - 1]   + s_t[sr * SDIM + sc + 1];
        const int diag  = s_t[(sr - 1) * SDIM + sc - 1] + s_t[(sr - 1) * SDIM + sc + 1]
                        + s_t[(sr + 1) * SDIM + sc - 1] + s_t[(sr + 1) * SDIM + sc + 1];
        const int far   = s_t[(sr - 2) * SDIM + sc] + s_t[(sr + 2) * SDIM + sc]
                        + s_t[sr * SDIM + sc - 2]   + s_t[sr * SDIM + sc + 2];
        const int w13 = 5 * t00 + 2 * cross + 2 * diag + far;

        // profit = (R/5) * W13 - 5*c   (R/5 = 0.96)
        const float profit = 0.96f * (float)w13 - 5.0f * (float)t00;

        const int gr = tileR0 + r;
        const int gc = tileC0 + c;
        const int i = gr * L + gc;

        float4 q = qtab[i];                 // q[i][0][0], [0][1], [1][0], [1][1]
        const float2 rv = rnd[i];

        const int A = t00;                  // current state
        const float qa0 = A ? q.z : q.x;
        const float qa1 = A ? q.w : q.y;

        // epsilon-greedy with jnp.argmax first-max tie-break semantics
        int greedy;
        if (qa0 > qa1)      greedy = 0;
        else if (qa1 > qa0) greedy = 1;
        else                greedy = ((1.0f + rv.y) > (1.0f + rv.x)) ? 1 : 0;

        const int B = (eps[i] >= 0.02f) ? greedy : rtype[i];

        // max_a' Q[B][a']
        const float qb0 = B ? q.z : q.x;
        const float qb1 = B ? q.w : q.y;
        const float maxv = fmaxf(qb0, qb1);

        // Q[A][B] update: (1-eta)*q + eta*(profit + gamma*maxv)
        const int ab = A * 2 + B;
        const float qab = (ab == 0) ? q.x : (ab == 1) ? q.y : (ab == 2) ? q.z : q.w;
        const float upd = 0.2f * qab + 0.8f * (profit + 0.8f * maxv);

        q.x = (ab == 0) ? upd : q.x;
        q.y = (ab == 1) ? upd : q.y;
        q.z = (ab == 2) ? upd : q.z;
        q.w = (ab == 3) ? upd : q.w;

        out_type[i]   = (float)B;
        out_q[i]      = q;
        out_profit[i] = profit;
    }
}

extern "C" void kernel_launch(void* const* d_in, const int* in_sizes, int n_in,
                              void* d_out, int out_size, void* d_ws, size_t ws_size,
                              hipStream_t stream) {
    const int*    type_t = (const int*)d_in[0];
    const float4* qtab   = (const float4*)d_in[1];
    const float2* rnd    = (const float2*)d_in[2];
    const int*    rtype  = (const int*)d_in[3];
    const float*  eps    = (const float*)d_in[4];

    float* out    = (float*)d_out;
    float* o_type = out;                       // N
    float4* o_q   = (float4*)(out + NCELL);    // 4N
    float* o_prof = out + 5 * (size_t)NCELL;   // N

    dim3 block(32, 8);
    dim3 grid(L / TILE, L / TILE);
    spgg_qlearn_kernel<<<grid, block, 0, stream>>>(
        type_t, qtab, rnd, rtype, eps, o_type, o_q, o_prof);
}

// Round 2
// 165.556 us; speedup vs baseline: 1.0044x; 1.0044x over previous
//
#include <hip/hip_runtime.h>

#define L 4096
#define LMASK 4095
#define NCELL (L * L)
#define TILE 32
#define HALO 2
#define SDIM (TILE + 2 * HALO)   // 36

__global__ __launch_bounds__(256) void spgg_qlearn_kernel(
    const int*    __restrict__ type_t,     // (L,L) int32, 0/1
    const float4* __restrict__ qtab,       // (N,2,2) f32 -> float4 per cell
    const float2* __restrict__ rnd,        // (N,2) f32 (tie-break only)
    const int*    __restrict__ rtype,      // (L,L) int32 0/1 (explore only)
    const float*  __restrict__ eps,        // (L,L) f32
    float*        __restrict__ out_type,   // (L,L) f32
    float4*       __restrict__ out_q,      // (N,2,2) f32
    float*        __restrict__ out_profit) // (L,L) f32
{
    __shared__ int s_t[SDIM * SDIM];

    const int tx = threadIdx.x;            // 0..31
    const int ty = threadIdx.y;            // 0..7
    const int tid = ty * 32 + tx;
    const int tileR0 = blockIdx.y * TILE;
    const int tileC0 = blockIdx.x * TILE;

    // Stage type tile with halo 2 (torus wrap via & mask, L = 2^12)
    for (int idx = tid; idx < SDIM * SDIM; idx += 256) {
        int ly = idx / SDIM;
        int lx = idx - ly * SDIM;
        int gr = (tileR0 + ly - HALO) & LMASK;
        int gc = (tileC0 + lx - HALO) & LMASK;
        s_t[idx] = type_t[gr * L + gc];
    }
    __syncthreads();

    #pragma unroll
    for (int k = 0; k < 4; ++k) {
        const int r = ty + k * 8;          // 0..31
        const int c = tx;
        const int sr = r + HALO;
        const int sc = c + HALO;

        // 13-point stencil == neigh5(neigh5(c)) with weights {5,2(cross),2(diag),1(far)}
        const int t00 = s_t[sr * SDIM + sc];
        const int cross = s_t[(sr - 1) * SDIM + sc] + s_t[(sr + 1) * SDIM + sc]
                        + s_t[sr * SDIM + sc - 1]   + s_t[sr * SDIM + sc + 1];
        const int diag  = s_t[(sr - 1) * SDIM + sc - 1] + s_t[(sr - 1) * SDIM + sc + 1]
                        + s_t[(sr + 1) * SDIM + sc - 1] + s_t[(sr + 1) * SDIM + sc + 1];
        const int far   = s_t[(sr - 2) * SDIM + sc] + s_t[(sr + 2) * SDIM + sc]
                        + s_t[sr * SDIM + sc - 2]   + s_t[sr * SDIM + sc + 2];
        const int w13 = 5 * t00 + 2 * cross + 2 * diag + far;

        // profit = (R/5) * W13 - 5*c   (R/5 = 0.96)
        const float profit = 0.96f * (float)w13 - 5.0f * (float)t00;

        const int gr = tileR0 + r;
        const int gc = tileC0 + c;
        const int i = gr * L + gc;

        float4 q = qtab[i];                 // q[i][0][0], [0][1], [1][0], [1][1]

        const int A = t00;                  // current state
        const float qa0 = A ? q.z : q.x;
        const float qa1 = A ? q.w : q.y;

        // epsilon-greedy; rnd only touched on exact ties (argmax over
        // masked+rand is decided by q alone otherwise)
        int greedy;
        if (qa0 > qa1) {
            greedy = 0;
        } else if (qa1 > qa0) {
            greedy = 1;
        } else {
            const float2 rv = rnd[i];
            greedy = ((1.0f + rv.y) > (1.0f + rv.x)) ? 1 : 0;
        }

        // rtype only touched on the 2% exploration lanes
        int B;
        const float e = eps[i];
        if (e >= 0.02f) {
            B = greedy;
        } else {
            B = rtype[i];
        }

        // max_a' Q[B][a'] from the ORIGINAL table
        const float qb0 = B ? q.z : q.x;
        const float qb1 = B ? q.w : q.y;
        const float maxv = fmaxf(qb0, qb1);

        // Q[A][B] update: (1-eta)*q + eta*(profit + gamma*maxv)
        const int ab = A * 2 + B;
        const float qab = (ab == 0) ? q.x : (ab == 1) ? q.y : (ab == 2) ? q.z : q.w;
        const float upd = 0.2f * qab + 0.8f * (profit + 0.8f * maxv);

        q.x = (ab == 0) ? upd : q.x;
        q.y = (ab == 1) ? upd : q.y;
        q.z = (ab == 2) ? upd : q.z;
        q.w = (ab == 3) ? upd : q.w;

        out_type[i]   = (float)B;
        out_q[i]      = q;
        out_profit[i] = profit;
    }
}

extern "C" void kernel_launch(void* const* d_in, const int* in_sizes, int n_in,
                              void* d_out, int out_size, void* d_ws, size_t ws_size,
                              hipStream_t stream) {
    const int*    type_t = (const int*)d_in[0];
    const float4* qtab   = (const float4*)d_in[1];
    const float2* rnd    = (const float2*)d_in[2];
    const int*    rtype  = (const int*)d_in[3];
    const float*  eps    = (const float*)d_in[4];

    float* out    = (float*)d_out;
    float* o_type = out;                       // N
    float4* o_q   = (float4*)(out + NCELL);    // 4N
    float* o_prof = out + 5 * (size_t)NCELL;   // N

    dim3 block(32, 8);
    dim3 grid(L / TILE, L / TILE);
    spgg_qlearn_kernel<<<grid, block, 0, stream>>>(
        type_t, qtab, rnd, rtype, eps, o_type, o_q, o_prof);
}